// Round 9
// baseline (2775.024 us; speedup 1.0000x reference)
//
#include <hip/hip_runtime.h>

#define N 4096
#define B 8
#define ITERS 10
#define T (ITERS * N)
#define NT 256          // 4 waves
#define E 16            // field elements per thread
#define WIN 1024
#define INFK 0xFFFFFFFFu
#define LIMIT 0x01000000u   // 1024<<14: max valid relative key span

// LDS-only barrier: inner-loop cross-wave traffic is LDS slots only ->
// lgkmcnt(0) suffices; in-flight global row loads stay in flight.
// Parity-buffered slots + 1 barrier/round is race-free.
__device__ __forceinline__ void lds_barrier() {
    asm volatile("s_waitcnt lgkmcnt(0)\n\ts_barrier" ::: "memory");
}

// Kernel 1: Z0[b][i] = sum_j W[i][j] * x[b][j], double accumulation.
// 2 rows per block (x re-read halved). (proven round 8)
__global__ __launch_bounds__(256) void z0_gemv(const float* __restrict__ W,
                                               const float* __restrict__ x,
                                               double* __restrict__ Z0) {
    const int i0 = 2 * blockIdx.x;
    const int tid = threadIdx.x;
    const int lane = tid & 63;
    const int wid = tid >> 6;
    const float4* __restrict__ row0 = (const float4*)(W + (size_t)i0 * N);
    const float4* __restrict__ row1 = (const float4*)(W + (size_t)(i0 + 1) * N);
    const float4* __restrict__ xv = (const float4*)x;

    double acc0[B], acc1[B];
#pragma unroll
    for (int b = 0; b < B; ++b) { acc0[b] = 0.0; acc1[b] = 0.0; }

#pragma unroll
    for (int it = 0; it < 4; ++it) {
        const int c = tid + 256 * it;
        const float4 w0 = row0[c];
        const float4 w1 = row1[c];
#pragma unroll
        for (int b = 0; b < B; ++b) {
            const float4 xb = xv[b * (N / 4) + c];
            acc0[b] += (double)w0.x * (double)xb.x + (double)w0.y * (double)xb.y +
                       (double)w0.z * (double)xb.z + (double)w0.w * (double)xb.w;
            acc1[b] += (double)w1.x * (double)xb.x + (double)w1.y * (double)xb.y +
                       (double)w1.z * (double)xb.z + (double)w1.w * (double)xb.w;
        }
    }

#pragma unroll
    for (int off = 32; off > 0; off >>= 1) {
#pragma unroll
        for (int b = 0; b < B; ++b) {
            acc0[b] += __shfl_down(acc0[b], off, 64);
            acc1[b] += __shfl_down(acc1[b], off, 64);
        }
    }

    __shared__ double red[4][2][B];
    if (lane == 0) {
#pragma unroll
        for (int b = 0; b < B; ++b) { red[wid][0][b] = acc0[b]; red[wid][1][b] = acc1[b]; }
    }
    __syncthreads();
    if (tid < B) {
        Z0[(size_t)tid * N + i0] =
            red[0][0][tid] + red[1][0][tid] + red[2][0][tid] + red[3][0][tid];
        Z0[(size_t)tid * N + i0 + 1] =
            red[0][1][tid] + red[1][1][tid] + red[2][1][tid] + red[3][1][tid];
    }
}

__device__ __forceinline__ unsigned umin2(unsigned a, unsigned b) { return a < b ? a : b; }
__device__ __forceinline__ unsigned umin4(unsigned a, unsigned b, unsigned c, unsigned d) {
    return umin2(umin2(a, b), umin2(c, d));
}

template <int CTRL>
__device__ __forceinline__ unsigned dpp_min(unsigned v) {
    const int t = __builtin_amdgcn_update_dpp((int)v, (int)v, CTRL, 0xF, 0xF, false);
    return umin2(v, (unsigned)t);
}

// 4-step row-min: lanes 15/31/47/63 hold the four 16-lane-group mins.
__device__ __forceinline__ unsigned quarter_min(unsigned v) {
    v = dpp_min<0x111>(v);  // row_shr:1
    v = dpp_min<0x112>(v);  // row_shr:2
    v = dpp_min<0x114>(v);  // row_shr:4
    v = dpp_min<0x118>(v);  // row_shr:8
    return v;
}

// Full-wave min (6 steps); valid in lane 63.
__device__ __forceinline__ unsigned full_min(unsigned v) {
    v = quarter_min(v);
    v = dpp_min<0x142>(v);  // row_bcast:15
    v = dpp_min<0x143>(v);  // row_bcast:31
    return v;
}

// tree min of 16 (compiler fuses to v_min3_u32 chains)
__device__ __forceinline__ unsigned min16(const unsigned* h) {
    return umin2(umin2(umin4(h[0], h[1], h[2], h[3]), umin4(h[4], h[5], h[6], h[7])),
                 umin2(umin4(h[8], h[9], h[10], h[11]), umin4(h[12], h[13], h[14], h[15])));
}
__device__ __forceinline__ void knock(unsigned* h, unsigned g) {
#pragma unroll
    for (int k = 0; k < 16; ++k) h[k] = (h[k] == g) ? INFK : h[k];
}

// Load this thread's 16-column fragment of row i into registers.
__device__ __forceinline__ void fetch_row(const float* __restrict__ W, int i,
                                          int tid, float* wr) {
    const float4* __restrict__ rp = (const float4*)(W + (size_t)i * N) + 4 * tid;
    const float4 a = rp[0], c = rp[1], e = rp[2], f = rp[3];
    wr[0] = a.x;  wr[1] = a.y;  wr[2] = a.z;  wr[3] = a.w;
    wr[4] = c.x;  wr[5] = c.y;  wr[6] = c.z;  wr[7] = c.w;
    wr[8] = e.x;  wr[9] = e.y;  wr[10] = e.z; wr[11] = e.w;
    wr[12] = f.x; wr[13] = f.y; wr[14] = f.z; wr[15] = f.w;
}

// toggle y/sk of element ii (one owner thread)
#define FIXUP(ii)                                                         \
    do {                                                                  \
        if (tid == ((ii) >> 4)) {                                         \
            const int kk = (ii) & 15;                                     \
            _Pragma("unroll") for (int k = 0; k < E; ++k) if (k == kk) {  \
                ym[k] ^= 0x80000000u;                                     \
                sk[k] ^= 2u;                                              \
            }                                                             \
        }                                                                 \
    } while (0)

// Row-cache lookup: W is read-only, so a cached row is NEVER stale ->
// index compare is the only correctness condition. Hit = ~30cy reg copy
// instead of ~450cy L3 fetch.
#define GETROW(ii, dst)                                                     \
    do {                                                                    \
        const int _i = (ii);                                                \
        if (_i == ci3) {                                                    \
            _Pragma("unroll") for (int k = 0; k < E; ++k) dst[k] = pf3[k];  \
        } else if (_i == ci4) {                                             \
            _Pragma("unroll") for (int k = 0; k < E; ++k) dst[k] = pf4[k];  \
        } else {                                                            \
            fetch_row(W, _i, tid, dst);                                     \
        }                                                                   \
    } while (0)

// Kernel 2: pair-commit rounds (proven k=2, rounds 6+8) + cross-round row
// cache: the success merge is extended to g3,g4 (likely round-after-next
// winners, survival ~ the measured 87% validity rate); their rows are
// prefetched into (ci3,pf3),(ci4,pf4). Next round's GETROW compares indices
// and reuses registers on hit, removing the winner-row fetch (~450cy, the
// dominant critical-path term) from most rounds. Validity is now resolved
// BEFORE the g1 merge so failure rounds issue their fetch earlier and also
// consult the cache. Validity semantics, key algebra, and exactness are
// unchanged from rounds 6/8.
__global__ __launch_bounds__(256, 1) void hop_seq(const float* __restrict__ W,
                                                  const float* __restrict__ x,
                                                  const int* __restrict__ perms,
                                                  const double* __restrict__ Z0,
                                                  float* __restrict__ out) {
    const int b = blockIdx.x;
    const int tid = threadIdx.x;
    const int wid = tid >> 6;
    const int lane = tid & 63;

    __shared__ int wpos[N];                         // 16 KB epoch-tagged inverse map
    __shared__ __align__(16) unsigned pubP[2][16];  // 4 quarter-mins x 4 waves, parity
    __shared__ __align__(16) unsigned pubV[2][4];   // validity min per wave, parity

    // ---- register-resident field ----
    double zj[E], zc[E];
    unsigned ym[E];                // 0xFFFFFFFF if y>0 else 0x7FFFFFFF
    unsigned sk[E];
    {
        const double* __restrict__ zsrc = Z0 + (size_t)b * N + E * tid;
#pragma unroll
        for (int k = 0; k < E; ++k) zj[k] = zsrc[k];
        const float4* __restrict__ xs = (const float4*)(x + (size_t)b * N);
#pragma unroll
        for (int q = 0; q < 4; ++q) {
            const float4 xv = xs[4 * tid + q];
            ym[4 * q + 0] = (xv.x > 0.f) ? 0xFFFFFFFFu : 0x7FFFFFFFu;
            ym[4 * q + 1] = (xv.y > 0.f) ? 0xFFFFFFFFu : 0x7FFFFFFFu;
            ym[4 * q + 2] = (xv.z > 0.f) ? 0xFFFFFFFFu : 0x7FFFFFFFu;
            ym[4 * q + 3] = (xv.w > 0.f) ? 0xFFFFFFFFu : 0x7FFFFFFFu;
        }
    }
    // zero-init inverse map (stale-tag hazard: LDS undefined at start)
    {
        const int4 z4 = make_int4(0, 0, 0, 0);
#pragma unroll
        for (int q = 0; q < 4; ++q) ((int4*)wpos)[tid + 256 * q] = z4;
    }
    lds_barrier();

    const int* __restrict__ perm_b = perms + (size_t)b * T;
    unsigned r = 0;                // barrier parity counter

    // ---- cross-round row cache (persists across windows; index-keyed) ----
    float pf3[E], pf4[E];
    int ci3 = -1, ci4 = -1;

    for (int base = 0; base < T; base += WIN) {
        const int epoch = (base >> 10) + 1;
        // scatter inverse map (window = permutation slice, indices distinct)
        const int4 iv = ((const int4*)(perm_b + base))[tid];
        wpos[iv.x] = (epoch << 10) | (4 * tid + 0);
        wpos[iv.y] = (epoch << 10) | (4 * tid + 1);
        wpos[iv.z] = (epoch << 10) | (4 * tid + 2);
        wpos[iv.w] = (epoch << 10) | (4 * tid + 3);
        lds_barrier();
        // build static keys for the 16 owned elems
#pragma unroll
        for (int q = 0; q < 4; ++q) {
            const int4 wp = ((const int4*)wpos)[4 * tid + q];
            const int e0 = 4 * q;
            const unsigned i0 = (unsigned)(E * tid + e0);
            sk[e0 + 0] = ((wp.x >> 10) == epoch)
                ? (((unsigned)(wp.x & 1023) << 14) | ((i0 + 0) << 2) | ((ym[e0 + 0] >> 30) & 2u)) : INFK;
            sk[e0 + 1] = ((wp.y >> 10) == epoch)
                ? (((unsigned)(wp.y & 1023) << 14) | ((i0 + 1) << 2) | ((ym[e0 + 1] >> 30) & 2u)) : INFK;
            sk[e0 + 2] = ((wp.z >> 10) == epoch)
                ? (((unsigned)(wp.z & 1023) << 14) | ((i0 + 2) << 2) | ((ym[e0 + 2] >> 30) & 2u)) : INFK;
            sk[e0 + 3] = ((wp.w >> 10) == epoch)
                ? (((unsigned)(wp.w & 1023) << 14) | ((i0 + 3) << 2) | ((ym[e0 + 3] >> 30) & 2u)) : INFK;
        }

        unsigned n = 0;                  // candidates carried this round (0/1/2)
        unsigned wk1 = 0, wk2 = 0;       // absolute keys of the pair
        unsigned ckR = 0;                // cursor for scan-only rounds
        float w1[E], w2[E];

        for (;;) {
            // ---- uniform decode + owner fixups ----
            unsigned ck1 = 0, ck2 = 0, ckP;
            int i1 = 0, i2 = 0;
            double d1 = 0.0, d2 = 0.0;
            if (n >= 1) {
                i1 = (int)((wk1 >> 2) & 4095u);
                d1 = (double)(-2 * ((int)(wk1 & 3u) - 1));
                ck1 = ((wk1 >> 14) + 1u) << 14;
                FIXUP(i1);
            }
            if (n == 2) {
                i2 = (int)((wk2 >> 2) & 4095u);
                d2 = (double)(-2 * ((int)(wk2 & 3u) - 1));
                ck2 = ((wk2 >> 14) + 1u) << 14;
                FIXUP(i2);
            }
            ckP = (n == 0) ? ckR : (n == 1) ? ck1 : ck2;

            // ---- fused pass: states + scan mins ----
            unsigned key1 = INFK, keyP = INFK;
            if (n == 2) {
#pragma unroll
                for (int k = 0; k < E; ++k) {
                    const double a = fma(d1, (double)w1[k], zj[k]);   // mid
                    zc[k] = a;
                    const unsigned tm = ((unsigned)__double2hiint(a)) ^ ym[k];
                    key1 = umin2(key1, (sk[k] | (unsigned)(((int)tm) >> 31)) - ck1);
                    const double c = fma(d2, (double)w2[k], a);       // post
                    zj[k] = c;
                    const unsigned tp = ((unsigned)__double2hiint(c)) ^ ym[k];
                    keyP = umin2(keyP, (sk[k] | (unsigned)(((int)tp) >> 31)) - ck2);
                }
            } else if (n == 1) {
#pragma unroll
                for (int k = 0; k < E; ++k) {
                    const double c = fma(d1, (double)w1[k], zj[k]);
                    zj[k] = c;
                    const unsigned tp = ((unsigned)__double2hiint(c)) ^ ym[k];
                    keyP = umin2(keyP, (sk[k] | (unsigned)(((int)tp) >> 31)) - ck1);
                }
            } else {
#pragma unroll
                for (int k = 0; k < E; ++k) {
                    const unsigned tp = ((unsigned)__double2hiint(zj[k])) ^ ym[k];
                    keyP = umin2(keyP, (sk[k] | (unsigned)(((int)tp) >> 31)) - ckR);
                }
            }

            // ---- trees: 4-step quarter chain (P) + 6-step full chain (V) ----
            const unsigned vP = quarter_min(keyP);
            const unsigned vV = full_min(key1);   // INFK when n<2

            // ---- publish (lanes 15/31/47/63 write directly) ----
            const unsigned p = r & 1u; ++r;
            if ((lane & 15) == 15) pubP[p][4 * wid + (lane >> 4)] = vP;
            if (lane == 63) pubV[p][wid] = vV;
            lds_barrier();

            // ---- validity FIRST (failure path issues its fetch earliest) ----
            const uint4 vv = *(const uint4*)&pubV[p][0];
            const uint4 q0 = *(const uint4*)&pubP[p][0];
            const uint4 q1 = *(const uint4*)&pubP[p][4];
            const uint4 q2 = *(const uint4*)&pubP[p][8];
            const uint4 q3 = *(const uint4*)&pubP[p][12];
            if (n == 2) {
                const unsigned gv = umin4(vv.x, vv.y, vv.z, vv.w);
                if (gv < ck2 - ck1) {
                    // FAILURE: i1 stays committed; rollback to mid, revert i2
                    const unsigned vabs = gv + ck1;
                    const bool dem = ((vabs >> 14) == (wk2 >> 14));
                    if (!dem) GETROW((int)((vabs >> 2) & 4095u), w1);  // issue ASAP
#pragma unroll
                    for (int k = 0; k < E; ++k) zj[k] = zc[k];
                    FIXUP(i2);
                    if (dem) {
                        // i2 de-mismatched at mid: fresh scan from its cursor
                        n = 0; ckR = ck2;
                    } else {
                        // interloper = true next winner; KEEP old (wk2, w2).
                        wk1 = vabs;
                    }
                    continue;
                }
            }

            // ---- SUCCESS: merge 16 quarter-mins; top-2 = next pair ----
            unsigned h[16];
            h[0] = q0.x;  h[1] = q0.y;  h[2] = q0.z;  h[3] = q0.w;
            h[4] = q1.x;  h[5] = q1.y;  h[6] = q1.z;  h[7] = q1.w;
            h[8] = q2.x;  h[9] = q2.y;  h[10] = q2.z; h[11] = q2.w;
            h[12] = q3.x; h[13] = q3.y; h[14] = q3.z; h[15] = q3.w;
            const unsigned g1 = min16(h);
            if (g1 >= LIMIT) break;        // window converged (state stands)
            wk1 = g1 + ckP; n = 1;
            GETROW((int)((wk1 >> 2) & 4095u), w1);
            knock(h, g1);
            const unsigned g2 = min16(h);
            if (g2 < LIMIT) {
                wk2 = g2 + ckP; n = 2;
                GETROW((int)((wk2 >> 2) & 4095u), w2);
                // ---- g3/g4: round-after-next predictions -> refill cache ----
                knock(h, g2);
                const unsigned g3 = min16(h);
                if (g3 < LIMIT) {
                    ci3 = (int)(((g3 + ckP) >> 2) & 4095u);
                    fetch_row(W, ci3, tid, pf3);
                    knock(h, g3);
                    const unsigned g4 = min16(h);
                    if (g4 < LIMIT) {
                        ci4 = (int)(((g4 + ckP) >> 2) & 4095u);
                        fetch_row(W, ci4, tid, pf4);
                    }
                }
            }
        }
    }

    // ---- output: y = +1 if ym top bit set else -1 ----
    float4* __restrict__ os = (float4*)(out + (size_t)b * N);
#pragma unroll
    for (int q = 0; q < 4; ++q) {
        float4 o;
        o.x = (ym[4 * q + 0] & 0x80000000u) ? 1.0f : -1.0f;
        o.y = (ym[4 * q + 1] & 0x80000000u) ? 1.0f : -1.0f;
        o.z = (ym[4 * q + 2] & 0x80000000u) ? 1.0f : -1.0f;
        o.w = (ym[4 * q + 3] & 0x80000000u) ? 1.0f : -1.0f;
        os[4 * tid + q] = o;
    }
}

extern "C" void kernel_launch(void* const* d_in, const int* in_sizes, int n_in,
                              void* d_out, int out_size, void* d_ws, size_t ws_size,
                              hipStream_t stream) {
    const float* x = (const float*)d_in[0];      // [B, N] f32, bipolar
    const float* W = (const float*)d_in[1];      // [N, N] f32, symmetric, zero diag
    const int* perms = (const int*)d_in[2];      // [B, ITERS, N] i32
    float* out = (float*)d_out;                  // [B, N] f32
    double* Z0 = (double*)d_ws;                  // B*N doubles = 256 KB scratch

    hipLaunchKernelGGL(z0_gemv, dim3(N / 2), dim3(256), 0, stream, W, x, Z0);
    hipLaunchKernelGGL(hop_seq, dim3(B), dim3(NT), 0, stream, W, x, perms, Z0, out);
}